// Round 3
// baseline (49.005 us; speedup 1.0000x reference)
//
#include <hip/hip_runtime.h>
#include <math.h>

namespace {

constexpr int BATCH = 16;
constexpr int Ww = 96;
constexpr int NP = 96 * 96;    // 9216
constexpr int NHYP = 128;
constexpr int HPB = 4;         // hypotheses per vote block
constexpr int GPB = NHYP / HPB;  // 32 vote blocks per batch

__device__ inline double waveSumD(double v) {
#pragma unroll
  for (int o = 32; o >= 1; o >>= 1) v += __shfl_xor(v, o, 64);
  return v;
}
__device__ inline int waveSumI(int v) {
#pragma unroll
  for (int o = 32; o >= 1; o >>= 1) v += __shfl_xor(v, o, 64);
  return v;
}

// ---------------- Kernel 1: hypotheses (f64, proven absmax 0.0) -------------
// 16 blocks x 128 threads. Solve 2x2 per hyp, batch stats (ddof=1), one-sided
// z>2 outlier replacement. Writes f64 table for the final reduction and a
// packed f32 table (yy, yx, weight-mult, nan-flag) for the vote kernel.
// Also zeroes the per-batch ticket counter (replaces a memset node).
__global__ __launch_bounds__(128)
void hyp_kernel(const float* __restrict__ uv, const int* __restrict__ pair,
                double* __restrict__ Ypd, float4* __restrict__ hypf,
                int* __restrict__ done) {
  __shared__ double sh[2];
  const int b = blockIdx.x;
  const int n = threadIdx.x;

  auto bsum128 = [&](double v) -> double {
    v = waveSumD(v);
    __syncthreads();
    if ((n & 63) == 0) sh[n >> 6] = v;
    __syncthreads();
    return sh[0] + sh[1];
  };

  int i0 = pair[(b * NHYP + n) * 2 + 0];
  int i1 = pair[(b * NHYP + n) * 2 + 1];
  const float* uvb = uv + (size_t)b * 2 * NP;
  double u0 = uvb[i0], v0 = uvb[NP + i0];
  double u1 = uvb[i1], v1 = uvb[NP + i1];
  double y0 = (double)(i0 / Ww), x0 = (double)(i0 % Ww);
  double y1 = (double)(i1 / Ww), x1 = (double)(i1 % Ww);
  // A = [[u0,-u1],[v0,-v1]], Bvec = [y1-y0, x1-x0]; s = (A^-1 Bvec).x
  double det = u1 * v0 - u0 * v1;
  double s = (u1 * (x1 - x0) - v1 * (y1 - y0)) / det;
  double Yy = s * u0 + y0;
  double Yx = s * v0 + x0;

  double my = bsum128(Yy) * (1.0 / NHYP);
  double mx = bsum128(Yx) * (1.0 / NHYP);
  double dy = Yy - my, dx = Yx - mx;
  double vy = bsum128(dy * dy) * (1.0 / (NHYP - 1));
  double vx = bsum128(dx * dx) * (1.0 / (NHYP - 1));
  bool outl = (dy / sqrt(vy) > 2.0) || (dx / sqrt(vx) > 2.0);  // NaN -> false
  double py = outl ? my : Yy;
  double px = outl ? mx : Yx;

  const int bn = b * NHYP + n;
  Ypd[bn * 2 + 0] = py;
  Ypd[bn * 2 + 1] = px;
  float4 hf;
  hf.x = (float)py;
  hf.y = (float)px;
  // h_in_mask==1 <=> trunc(Yp) hits a lattice point <=> Yp in (-1,96)^2
  hf.z = (py > -1.0 && py < 96.0 && px > -1.0 && px < 96.0) ? 10.0f : 1.0f;
  hf.w = (isnan(py) || isnan(px)) ? 1.0f : 0.0f;
  hypf[bn] = hf;
  if (n == 0) done[b] = 0;
}

// ------------- Kernel 2: votes + (ticketed) final reduction -----------------
// 512 blocks x 256 threads; block owns (batch b, 4 hypotheses). Each thread
// processes 4 consecutive pixels per iteration (float4 loads; 96%4==0 so a
// group never crosses a row). Vote test: yy*u + yx*v > c, c = y*u + x*v
// (normalization in the reference is sign-preserving; NaN -> false).
__global__ __launch_bounds__(256)
void vote_final_kernel(const float* __restrict__ uv,
                       const double* __restrict__ Ypd,
                       const float4* __restrict__ hypf,
                       int* __restrict__ counts, int* __restrict__ done,
                       float* __restrict__ out) {
  const int t = threadIdx.x;
  const int b = blockIdx.x >> 5;        // / GPB
  const int g = blockIdx.x & (GPB - 1);
  const float* uvb = uv + (size_t)b * 2 * NP;

  float yy[HPB], yx[HPB];
#pragma unroll
  for (int h = 0; h < HPB; ++h) {
    float4 hf = hypf[b * NHYP + g * HPB + h];   // wave-uniform -> scalar loads
    yy[h] = hf.x;
    yx[h] = hf.y;
  }

  int cnt[HPB] = {0, 0, 0, 0};
#pragma unroll
  for (int it = 0; it < 9; ++it) {
    const int p = (it * 256 + t) * 4;
    const float4 u4 = *(const float4*)(uvb + p);
    const float4 v4 = *(const float4*)(uvb + NP + p);
    const int yi = p / Ww;
    const float fy = (float)yi;
    const float fx = (float)(p - yi * Ww);
    const float c0 = fy * u4.x + fx * v4.x;
    const float c1 = fy * u4.y + (fx + 1.0f) * v4.y;
    const float c2 = fy * u4.z + (fx + 2.0f) * v4.z;
    const float c3 = fy * u4.w + (fx + 3.0f) * v4.w;
#pragma unroll
    for (int h = 0; h < HPB; ++h) {
      cnt[h] += (fmaf(yy[h], u4.x, yx[h] * v4.x) > c0) ? 1 : 0;
      cnt[h] += (fmaf(yy[h], u4.y, yx[h] * v4.y) > c1) ? 1 : 0;
      cnt[h] += (fmaf(yy[h], u4.z, yx[h] * v4.z) > c2) ? 1 : 0;
      cnt[h] += (fmaf(yy[h], u4.w, yx[h] * v4.w) > c3) ? 1 : 0;
    }
  }

  __shared__ int sC[4][HPB];
#pragma unroll
  for (int h = 0; h < HPB; ++h) {
    int r = waveSumI(cnt[h]);
    if ((t & 63) == 0) sC[t >> 6][h] = r;
  }
  __syncthreads();
  if (t < HPB) {
    int tot = sC[0][t] + sC[1][t] + sC[2][t] + sC[3][t];
    __hip_atomic_store(&counts[b * NHYP + g * HPB + t], tot, __ATOMIC_RELAXED,
                       __HIP_MEMORY_SCOPE_AGENT);   // coherent across XCDs
  }

  // completion ticket
  __shared__ int sPrev;
  __syncthreads();
  __threadfence();
  if (t == 0) sPrev = atomicAdd(&done[b], 1);
  __syncthreads();
  if (sPrev != GPB - 1) return;

  // ---- last block of batch: weights + weighted mean (f64) ----
  __threadfence();
  __shared__ double sD[4];
  auto bsum = [&](double v) -> double {
    double r = waveSumD(v);
    __syncthreads();
    if ((t & 63) == 0) sD[t >> 6] = r;
    __syncthreads();
    return sD[0] + sD[1] + sD[2] + sD[3];
  };

  double w = 0.0, py = 0.0, px = 0.0;
  bool nan = false;
  if (t < NHYP) {
    int cv = __hip_atomic_load(&counts[b * NHYP + t], __ATOMIC_RELAXED,
                               __HIP_MEMORY_SCOPE_AGENT);
    float4 hf = hypf[b * NHYP + t];
    w = (double)cv * (double)hf.z;
    nan = (hf.w != 0.0f);
    py = Ypd[(b * NHYP + t) * 2 + 0];
    px = Ypd[(b * NHYP + t) * 2 + 1];
  }
  double wsum = bsum(w);
  double wn = (t < NHYP && !nan) ? w / wsum : 0.0;
  if (nan) { py = 0.0; px = 0.0; }   // avoid NaN*0 polluting the sum
  double oy = bsum(py * wn);
  double ox = bsum(px * wn);
  if (t == 0) {
    out[b * 2 + 0] = (float)ox;   // weighted_mean[:, ::-1]
    out[b * 2 + 1] = (float)oy;
  }
}

}  // namespace

extern "C" void kernel_launch(void* const* d_in, const int* in_sizes, int n_in,
                              void* d_out, int out_size, void* d_ws, size_t ws_size,
                              hipStream_t stream) {
  const float* uv = (const float*)d_in[0];   // (16,2,96,96) f32
  // d_in[1] = mask, unused (all ones; never read by the reference math)
  const int* pair = (const int*)d_in[2];     // (16,128,2) i32
  float* out = (float*)d_out;                // (16,2) f32

  char* ws = (char*)d_ws;
  double* Ypd  = (double*)ws;                         // 16*128*2*8 = 32768 B
  float4* hypf = (float4*)(ws + 32768);               // 16*128*16  = 32768 B
  int* counts  = (int*)(ws + 65536);                  // 16*128*4   =  8192 B
  int* done    = (int*)(ws + 65536 + 8192);           // 16*4       =    64 B

  hyp_kernel<<<BATCH, NHYP, 0, stream>>>(uv, pair, Ypd, hypf, done);
  vote_final_kernel<<<BATCH * GPB, 256, 0, stream>>>(uv, Ypd, hypf, counts,
                                                     done, out);
}

// Round 4
// 18.055 us; speedup vs baseline: 2.7141x; 2.7141x over previous
//
#include <hip/hip_runtime.h>
#include <math.h>

namespace {

constexpr int BATCH = 16;
constexpr int Ww = 96;
constexpr int NP = 96 * 96;     // 9216
constexpr int NHYP = 128;
constexpr int HPB = 2;          // hypotheses per vote block
constexpr int GPB = NHYP / HPB; // 64 vote blocks per batch

__device__ inline void waveSum2D(double& a, double& b) {
#pragma unroll
  for (int o = 32; o >= 1; o >>= 1) {
    a += __shfl_xor(a, o, 64);
    b += __shfl_xor(b, o, 64);
  }
}
__device__ inline void waveSum2I(int& a, int& b) {
#pragma unroll
  for (int o = 32; o >= 1; o >>= 1) {
    a += __shfl_xor(a, o, 64);
    b += __shfl_xor(b, o, 64);
  }
}
__device__ inline double waveSumD(double v) {
#pragma unroll
  for (int o = 32; o >= 1; o >>= 1) v += __shfl_xor(v, o, 64);
  return v;
}

// ---------------- Kernel 1: hypotheses (f64, proven absmax 0.0) -------------
// 16 blocks x 128 threads. 2x2 solve per hyp, batch stats (ddof=1, two-pass),
// one-sided z>2 outlier replacement. Writes f64 table (final reduction) and
// packed f32 table (yy, yx, weight-mult, nan-flag) for the vote kernel.
__global__ __launch_bounds__(128)
void hyp_kernel(const float* __restrict__ uv, const int* __restrict__ pair,
                double* __restrict__ Ypd, float4* __restrict__ hypf) {
  __shared__ double sh[2][2];
  const int b = blockIdx.x;
  const int n = threadIdx.x;
  const int lane = n & 63;
  const int w = n >> 6;

  int i0 = pair[(b * NHYP + n) * 2 + 0];
  int i1 = pair[(b * NHYP + n) * 2 + 1];
  const float* uvb = uv + (size_t)b * 2 * NP;
  double u0 = uvb[i0], v0 = uvb[NP + i0];
  double u1 = uvb[i1], v1 = uvb[NP + i1];
  double y0 = (double)(i0 / Ww), x0 = (double)(i0 % Ww);
  double y1 = (double)(i1 / Ww), x1 = (double)(i1 % Ww);
  // A = [[u0,-u1],[v0,-v1]], Bvec = [y1-y0, x1-x0]; s = (A^-1 Bvec).x
  double det = u1 * v0 - u0 * v1;
  double s = (u1 * (x1 - x0) - v1 * (y1 - y0)) / det;
  double Yy = s * u0 + y0;
  double Yx = s * v0 + x0;

  // pass 1: means (paired reduction for ILP)
  double sy = Yy, sx = Yx;
  waveSum2D(sy, sx);
  if (lane == 0) { sh[w][0] = sy; sh[w][1] = sx; }
  __syncthreads();
  double my = (sh[0][0] + sh[1][0]) * (1.0 / NHYP);
  double mx = (sh[0][1] + sh[1][1]) * (1.0 / NHYP);
  // pass 2: variances
  double dy = Yy - my, dx = Yx - mx;
  double qy = dy * dy, qx = dx * dx;
  waveSum2D(qy, qx);
  __syncthreads();
  if (lane == 0) { sh[w][0] = qy; sh[w][1] = qx; }
  __syncthreads();
  double vy = (sh[0][0] + sh[1][0]) * (1.0 / (NHYP - 1));
  double vx = (sh[0][1] + sh[1][1]) * (1.0 / (NHYP - 1));
  bool outl = (dy / sqrt(vy) > 2.0) || (dx / sqrt(vx) > 2.0);  // NaN -> false
  double py = outl ? my : Yy;
  double px = outl ? mx : Yx;

  const int bn = b * NHYP + n;
  Ypd[bn * 2 + 0] = py;
  Ypd[bn * 2 + 1] = px;
  float4 hf;
  hf.x = (float)py;
  hf.y = (float)px;
  // h_in_mask==1 <=> trunc(Yp) hits a lattice point <=> Yp in (-1,96)^2
  hf.z = (py > -1.0 && py < 96.0 && px > -1.0 && px < 96.0) ? 10.0f : 1.0f;
  hf.w = (isnan(py) || isnan(px)) ? 1.0f : 0.0f;
  hypf[bn] = hf;
}

// ---------------- Kernel 2: votes -------------------------------------------
// 1024 blocks x 256 threads; block owns (batch b, 2 hypotheses). Each thread
// tests 4 consecutive pixels per iteration (float4 loads; 96%4==0 so a group
// never crosses a row). Vote test: yy*u + yx*v > c with c = y*u + x*v
// (the reference's normalization is sign-preserving; NaN -> false).
// Each (b,hyp) count has exactly one owning block -> plain stores, no atomics,
// no fences (fences caused the round-2/3 L2-invalidation regression).
__global__ __launch_bounds__(256)
void vote_kernel(const float* __restrict__ uv, const float4* __restrict__ hypf,
                 int* __restrict__ counts) {
  const int t = threadIdx.x;
  const int b = blockIdx.x >> 6;          // / GPB
  const int g = blockIdx.x & (GPB - 1);
  const float* uvb = uv + (size_t)b * 2 * NP;

  const float4 h0 = hypf[b * NHYP + g * HPB + 0];   // uniform -> scalar loads
  const float4 h1 = hypf[b * NHYP + g * HPB + 1];

  int c0 = 0, c1 = 0;
#pragma unroll
  for (int it = 0; it < 9; ++it) {
    const int p = (it * 256 + t) * 4;
    const float4 u4 = *(const float4*)(uvb + p);
    const float4 v4 = *(const float4*)(uvb + NP + p);
    const int yi = p / Ww;
    const float fy = (float)yi;
    const float fx = (float)(p - yi * Ww);
    const float k0 = fy * u4.x + fx * v4.x;
    const float k1 = fy * u4.y + (fx + 1.0f) * v4.y;
    const float k2 = fy * u4.z + (fx + 2.0f) * v4.z;
    const float k3 = fy * u4.w + (fx + 3.0f) * v4.w;
    c0 += (fmaf(h0.x, u4.x, h0.y * v4.x) > k0) ? 1 : 0;
    c0 += (fmaf(h0.x, u4.y, h0.y * v4.y) > k1) ? 1 : 0;
    c0 += (fmaf(h0.x, u4.z, h0.y * v4.z) > k2) ? 1 : 0;
    c0 += (fmaf(h0.x, u4.w, h0.y * v4.w) > k3) ? 1 : 0;
    c1 += (fmaf(h1.x, u4.x, h1.y * v4.x) > k0) ? 1 : 0;
    c1 += (fmaf(h1.x, u4.y, h1.y * v4.y) > k1) ? 1 : 0;
    c1 += (fmaf(h1.x, u4.z, h1.y * v4.z) > k2) ? 1 : 0;
    c1 += (fmaf(h1.x, u4.w, h1.y * v4.w) > k3) ? 1 : 0;
  }

  waveSum2I(c0, c1);
  __shared__ int sC[4][HPB];
  if ((t & 63) == 0) { sC[t >> 6][0] = c0; sC[t >> 6][1] = c1; }
  __syncthreads();
  if (t < HPB)
    counts[b * NHYP + g * HPB + t] =
        sC[0][t] + sC[1][t] + sC[2][t] + sC[3][t];
}

// ---------------- Kernel 3: weights + weighted mean (f64) -------------------
__global__ __launch_bounds__(128)
void final_kernel(const double* __restrict__ Ypd,
                  const float4* __restrict__ hypf,
                  const int* __restrict__ counts, float* __restrict__ out) {
  __shared__ double sh[2][2];
  const int b = blockIdx.x;
  const int n = threadIdx.x;
  const int lane = n & 63;
  const int w = n >> 6;
  const int bn = b * NHYP + n;

  float4 hf = hypf[bn];
  double py = Ypd[bn * 2 + 0];
  double px = Ypd[bn * 2 + 1];
  double wgt = (double)counts[bn] * (double)hf.z;
  bool nan = (hf.w != 0.0f);

  double wsum = waveSumD(wgt);
  if (lane == 0) sh[w][0] = wsum;
  __syncthreads();
  wsum = sh[0][0] + sh[1][0];

  double wn = nan ? 0.0 : wgt / wsum;
  if (nan) { py = 0.0; px = 0.0; }    // keep NaN out of the sum
  double oy = py * wn, ox = px * wn;
  waveSum2D(oy, ox);
  __syncthreads();
  if (lane == 0) { sh[w][0] = oy; sh[w][1] = ox; }
  __syncthreads();
  if (n == 0) {
    out[b * 2 + 0] = (float)(sh[0][1] + sh[1][1]);  // weighted_mean[:, ::-1]
    out[b * 2 + 1] = (float)(sh[0][0] + sh[1][0]);
  }
}

}  // namespace

extern "C" void kernel_launch(void* const* d_in, const int* in_sizes, int n_in,
                              void* d_out, int out_size, void* d_ws, size_t ws_size,
                              hipStream_t stream) {
  const float* uv = (const float*)d_in[0];   // (16,2,96,96) f32
  // d_in[1] = mask, unused (all ones; never read by the reference math)
  const int* pair = (const int*)d_in[2];     // (16,128,2) i32
  float* out = (float*)d_out;                // (16,2) f32

  char* ws = (char*)d_ws;
  double* Ypd  = (double*)ws;                // 16*128*2*8 = 32768 B
  float4* hypf = (float4*)(ws + 32768);      // 16*128*16  = 32768 B
  int* counts  = (int*)(ws + 65536);         // 16*128*4   =  8192 B

  hyp_kernel<<<BATCH, NHYP, 0, stream>>>(uv, pair, Ypd, hypf);
  vote_kernel<<<BATCH * GPB, 256, 0, stream>>>(uv, hypf, counts);
  final_kernel<<<BATCH, NHYP, 0, stream>>>(Ypd, hypf, counts, out);
}